// Round 6
// baseline (129.189 us; speedup 1.0000x reference)
//
#include <hip/hip_runtime.h>

typedef unsigned short u16;
typedef unsigned int u32;
typedef __attribute__((ext_vector_type(4))) unsigned short u16x4;
typedef __attribute__((ext_vector_type(8))) unsigned short u16x8;
typedef __attribute__((ext_vector_type(8))) __bf16 bf16x8;
typedef __attribute__((ext_vector_type(4))) float f32x4;
typedef __attribute__((ext_vector_type(16))) float f32x16;
typedef __attribute__((ext_vector_type(2))) int i32x2;

#define S_LEN 2048
#define HDIM 1024
#define NHEAD 16
#define HD 64
#define MTOK 4096            // B*S
#define QKV_STRIDE 4194304   // elements per q/k/v plane
#define LOG2E 1.44269504089f
#define QKSCL (0.125f * 1.44269504089f)

__device__ __forceinline__ float bf2f(u16 h) {
    unsigned u = ((unsigned)h) << 16;
    return __builtin_bit_cast(float, u);
}
__device__ __forceinline__ u16 f2bf(float f) {
    return __builtin_bit_cast(u16, (__bf16)f);   // native v_cvt, RNE
}
__device__ __forceinline__ bf16x8 as_bf16(u16x8 u) {
    union { u16x8 a; bf16x8 b; } c; c.a = u; return c.b;
}
__device__ __forceinline__ void gld_lds16(const u16* g, u16* l) {
    __builtin_amdgcn_global_load_lds((const __attribute__((address_space(1))) u16*)g,
                                     (__attribute__((address_space(3))) u16*)l, 16, 0, 0);
}

// exchange: a' = (a_lo | b_lo^swap), b' = (a_hi^swap | b_hi)  across lane<32 / lane>=32
__device__ __forceinline__ void pl32swap(u32& a, u32& b) {
#if __has_builtin(__builtin_amdgcn_permlane32_swap)
    i32x2 r = __builtin_amdgcn_permlane32_swap((int)a, (int)b, false, false);
    a = (u32)r[0]; b = (u32)r[1];
#else
    u32 as = (u32)__shfl_xor((int)a, 32);
    u32 bs = (u32)__shfl_xor((int)b, 32);
    bool hi = (threadIdx.x & 32) != 0;
    u32 na = hi ? bs : a;
    u32 nb = hi ? b : as;
    a = na; b = nb;
#endif
}

// ---------------- fused preprocessing: casts + bias concat ----------------
__device__ __forceinline__ void cast4(const float* __restrict__ s, u16* __restrict__ d, int i) {
    f32x4 v = *(const f32x4*)(s + (size_t)i * 4);
    u16x4 o;
    o[0] = f2bf(v[0]); o[1] = f2bf(v[1]); o[2] = f2bf(v[2]); o[3] = f2bf(v[3]);
    *(u16x4*)(d + (size_t)i * 4) = o;
}

__global__ __launch_bounds__(256) void prep(const float* __restrict__ hs,
                                            const float* __restrict__ Wq, const float* __restrict__ Wk,
                                            const float* __restrict__ Wv, const float* __restrict__ Wd,
                                            const float* __restrict__ bq, const float* __restrict__ bk,
                                            const float* __restrict__ bv,
                                            u16* __restrict__ hsb, u16* __restrict__ wqkvb,
                                            u16* __restrict__ wdb, float* __restrict__ b3) {
    int bid = blockIdx.x, tid = threadIdx.x;
    if (bid < 4096) {
        cast4(hs, hsb, bid * 256 + tid);
    } else if (bid < 5120) {
        cast4(Wq, wqkvb, (bid - 4096) * 256 + tid);
    } else if (bid < 6144) {
        cast4(Wk, wqkvb + HDIM * HDIM, (bid - 5120) * 256 + tid);
    } else if (bid < 7168) {
        cast4(Wv, wqkvb + 2 * HDIM * HDIM, (bid - 6144) * 256 + tid);
    } else if (bid < 8192) {
        cast4(Wd, wdb, (bid - 7168) * 256 + tid);
    } else {
        int i = (bid - 8192) * 256 + tid;
        if (i < 3072) b3[i] = (i < 1024) ? bq[i] : (i < 2048) ? bk[i - 1024] : bv[i - 2048];
    }
}

// ---------------- GEMM: C[M,N] = A[M,K] * Bw[N,K]^T + bias ----------------
// 2-phase pipeline: dbuf LDS, stage-next before compute, counted vmcnt, raw barriers.
template <int MODE>
__global__ __launch_bounds__(256, 3) void gemm_bt(const u16* __restrict__ A, const u16* __restrict__ Bw,
                                                  const float* __restrict__ bias,
                                                  u16* __restrict__ outb, u16* __restrict__ vtout,
                                                  float* __restrict__ outf,
                                                  int Md, int Nd, int Kd) {
    __shared__ alignas(16) u16 As[2][128 * 32];
    __shared__ alignas(16) u16 Bs[2][128 * 32];
    const int tid = threadIdx.x;
    const int wave = tid >> 6, lane = tid & 63;
    const int l15 = lane & 15, l4 = lane >> 4;
    const int m0 = blockIdx.y * 128, n0 = blockIdx.x * 128;
    const int wm = wave >> 1, wn = wave & 1;

    const int cc0 = wave * 2;
    const int srow = lane >> 2;          // 0..15
    const int sco = (lane & 3) * 8;      // 0,8,16,24

    f32x4 acc[4][4];
#pragma unroll
    for (int i = 0; i < 4; i++)
#pragma unroll
        for (int j = 0; j < 4; j++) acc[i][j] = (f32x4){0.f, 0.f, 0.f, 0.f};

    auto STAGE = [&](int k0, int buf) {
#pragma unroll
        for (int i = 0; i < 2; i++) {
            int cc = cc0 + i;
            int row = cc * 16 + srow;
            gld_lds16(A + (size_t)(m0 + row) * Kd + k0 + sco, &As[buf][cc * 512]);
            gld_lds16(Bw + (size_t)(n0 + row) * Kd + k0 + sco, &Bs[buf][cc * 512]);
        }
    };

    const int nt = Kd >> 5;
    STAGE(0, 0);
    for (int t = 0; t < nt; ++t) {
        __builtin_amdgcn_s_barrier();                       // all waves done computing t-1
        if (t + 1 < nt) {
            STAGE((t + 1) << 5, (t + 1) & 1);
            asm volatile("s_waitcnt vmcnt(4)" ::: "memory");   // tile t's 4 loads landed
        } else {
            asm volatile("s_waitcnt vmcnt(0)" ::: "memory");
        }
        __builtin_amdgcn_s_barrier();                       // tile t visible to all
        const u16* as = &As[t & 1][0];
        const u16* bs = &Bs[t & 1][0];
        bf16x8 af[4], bf[4];
#pragma unroll
        for (int x = 0; x < 4; x++) {
            af[x] = as_bf16(*(const u16x8*)&as[(wm * 64 + x * 16 + l15) * 32 + l4 * 8]);
            bf[x] = as_bf16(*(const u16x8*)&bs[(wn * 64 + x * 16 + l15) * 32 + l4 * 8]);
        }
        __builtin_amdgcn_s_setprio(1);
#pragma unroll
        for (int mi = 0; mi < 4; mi++)
#pragma unroll
            for (int nj = 0; nj < 4; nj++)
                acc[mi][nj] = __builtin_amdgcn_mfma_f32_16x16x32_bf16(af[mi], bf[nj], acc[mi][nj], 0, 0, 0);
        __builtin_amdgcn_s_setprio(0);
    }

#pragma unroll
    for (int mi = 0; mi < 4; mi++) {
#pragma unroll
        for (int nj = 0; nj < 4; nj++) {
            int coln = n0 + wn * 64 + nj * 16 + l15;
            float bv_ = bias[coln];
            int rowb = m0 + wm * 64 + mi * 16 + l4 * 4;
            if (MODE == 0) {
                int which = coln >> 10, nn = coln & 1023;
                int hh = nn >> 6, dd = nn & 63;
                int bb = rowb >> 11, ss = rowb & 2047;
                if (which < 2) {
#pragma unroll
                    for (int r = 0; r < 4; r++)
                        outb[(size_t)which * QKV_STRIDE + ((size_t)((bb << 4) + hh) * S_LEN + ss + r) * HD + dd] =
                            f2bf(acc[mi][nj][r] + bv_);
                } else {
                    u16x4 o;
#pragma unroll
                    for (int r = 0; r < 4; r++) o[r] = f2bf(acc[mi][nj][r] + bv_);
                    *(u16x4*)(vtout + ((size_t)((bb << 4) + hh) * HD + dd) * S_LEN + ss) = o;
                }
            } else {
#pragma unroll
                for (int r = 0; r < 4; r++)
                    outf[(size_t)(rowb + r) * Nd + coln] = acc[mi][nj][r] + bv_;
            }
        }
    }
}

// ---------------- flash attention v6: 32x32 MFMA, in-register P, kv-split groups ----------------
// grid 512, block 512 (8 waves = 2 kv-groups x 4 q-strips of 32 rows). XCD-aware.
__global__ __launch_bounds__(512, 4) void flash_attn6(const u16* __restrict__ qkv,
                                                      const u16* __restrict__ vt,
                                                      const float* __restrict__ amask,
                                                      u16* __restrict__ ctx) {
    // [0,64K): per-group K/V double buffers (group g at g*32KB: K buf0|K buf1|V buf0|V buf1, 8KB each)
    // [64K,72K): mask f32[2048]
    // epilogue aliases [0,32K) as Oex f32 [4 strips][64 d][32 q], [32K,+512) as lsum
    __shared__ alignas(16) char smem[73728];

    const int tid = threadIdx.x;
    const int wave = tid >> 6, lane = tid & 63;
    const int l31 = lane & 31;
    const int hi = lane >> 5;           // 0/1
    const int hi4 = hi * 4;
    const int ws = wave & 3;            // q-strip
    const int g = wave >> 2;            // kv parity group

    // XCD-aware: each XCD (blockIdx.x % 8) owns 4 heads x 16 q-tiles
    const int lid = blockIdx.x;
    const int idx = lid >> 3;
    const int bh = (lid & 7) * 4 + (idx >> 4);
    const int qx = idx & 15;
    const int b = bh >> 4, h = bh & 15;
    const int qr0 = qx * 128 + ws * 32;

    const u16* qh = qkv + (size_t)bh * (S_LEN * HD);
    const u16* kh = qh + QKV_STRIDE;
    const u16* vth = vt + (size_t)bh * (S_LEN * HD);   // V^T [64][2048]

    u16* kbase = (u16*)(smem + g * 32768);
    u16* vbase = kbase + 8192;
    float* Ml = (float*)(smem + 65536);

    // mask -> LDS f32, pre-scaled by log2(e)
    {
        f32x4 m = *(const f32x4*)(amask + (size_t)b * S_LEN + tid * 4);
#pragma unroll
        for (int j = 0; j < 4; j++) m[j] *= LOG2E;
        *(f32x4*)&Ml[tid * 4] = m;
    }

    // Q B-fragments: B[k=d=s*16+hi*8+j][col=q=l31], 4 d-steps cover d=64
    bf16x8 qf[4];
#pragma unroll
    for (int s = 0; s < 4; ++s)
        qf[s] = as_bf16(*(const u16x8*)(qh + (size_t)(qr0 + l31) * HD + s * 16 + hi * 8));

    __syncthreads();   // mask + Q visible/consumed; vmcnt clean before staging

    // staging: per-wave 16 K-rows + 16 V^T-rows, source chunk pre-XOR-swizzled, LDS linear
    const int srow = lane >> 3;                       // 0..7
    const int schunk = (lane & 7) ^ srow;             // XOR swizzle
    const u16* kss = kh + (size_t)(ws * 16 + srow) * HD + schunk * 8;
    const u16* vss = vth + (size_t)(ws * 16 + srow) * S_LEN + schunk * 8;

    f32x16 oacc[2];
#pragma unroll
    for (int d = 0; d < 2; ++d)
#pragma unroll
        for (int i = 0; i < 16; ++i) oacc[d][i] = 0.f;
    float l_run = 0.f;

    auto STAGE = [&](int tloc, int buf) {
        const int kv0 = ((tloc << 1) + g) << 6;
        const u16* ks = kss + (size_t)kv0 * HD;
        const u16* vs = vss + kv0;
        u16* kd = kbase + buf * 4096 + ws * 1024;
        u16* vd = vbase + buf * 4096 + ws * 1024;
        gld_lds16(ks, kd);
        gld_lds16(ks + 8 * HD, kd + 512);
        gld_lds16(vs, vd);
        gld_lds16(vs + 8 * S_LEN, vd + 512);
    };

    auto tile = [&](int tloc, int buf) {
        const int kv0 = ((tloc << 1) + g) << 6;
        const u16* kb = kbase + buf * 4096;
        const u16* vb = vbase + buf * 4096;
#pragma unroll
        for (int sub = 0; sub < 2; ++sub) {
            // QK^T swapped: S^T[kv 32][q 32], A=K rows, B=Q
            f32x16 accs;
#pragma unroll
            for (int i = 0; i < 16; ++i) accs[i] = 0.f;
            const int kvrow = sub * 32 + l31;
            const int ksw = (kvrow & 7) << 3;
            __builtin_amdgcn_s_setprio(1);
#pragma unroll
            for (int s = 0; s < 4; ++s) {
                bf16x8 kf = as_bf16(*(const u16x8*)&kb[kvrow * 64 + (((s * 2 + hi) << 3) ^ ksw)]);
                accs = __builtin_amdgcn_mfma_f32_32x32x16_bf16(kf, qf[s], accs, 0, 0, 0);
            }
            __builtin_amdgcn_s_setprio(0);
            // softmax: lane owns q=l31; reg rg*4+rr -> kv = sub*32 + rg*8 + hi*4 + rr
            u32 pw_[8];
#pragma unroll
            for (int rg = 0; rg < 4; ++rg) {
                f32x4 mk = *(const f32x4*)&Ml[kv0 + sub * 32 + rg * 8 + hi4];
#pragma unroll
                for (int r2 = 0; r2 < 2; ++r2) {
                    float pa = __builtin_amdgcn_exp2f(accs[rg * 4 + r2 * 2] * QKSCL + mk[r2 * 2]);
                    float pb = __builtin_amdgcn_exp2f(accs[rg * 4 + r2 * 2 + 1] * QKSCL + mk[r2 * 2 + 1]);
                    l_run += pa + pb;
                    pw_[rg * 2 + r2] = (u32)f2bf(pa) | ((u32)f2bf(pb) << 16);
                }
            }
            // in-register P^T B-frags via lane<32/lane>=32 swap (T12)
            pl32swap(pw_[0], pw_[2]);
            pl32swap(pw_[1], pw_[3]);
            pl32swap(pw_[4], pw_[6]);
            pl32swap(pw_[5], pw_[7]);
            union { u32 w[4]; u16x8 v; } f0, f1;
            f0.w[0] = pw_[0]; f0.w[1] = pw_[1]; f0.w[2] = pw_[2]; f0.w[3] = pw_[3];
            f1.w[0] = pw_[4]; f1.w[1] = pw_[5]; f1.w[2] = pw_[6]; f1.w[3] = pw_[7];
            bf16x8 pf0 = as_bf16(f0.v), pf1 = as_bf16(f1.v);
            // PV swapped: O^T[d][q] += V^T[d][kv] * P^T[kv][q], kv steps sub*32+{0,16}
            __builtin_amdgcn_s_setprio(1);
#pragma unroll
            for (int dsub = 0; dsub < 2; ++dsub) {
                const int drow = dsub * 32 + l31;
                const int dsw = (drow & 7) << 3;
                const int c0 = (sub * 4 + hi) << 3;       // kv chunk for step0: (sub*2)*2+hi
                const int c1 = ((sub * 2 + 1) * 2 + hi) << 3;
                bf16x8 vf0 = as_bf16(*(const u16x8*)&vb[drow * 64 + (c0 ^ dsw)]);
                oacc[dsub] = __builtin_amdgcn_mfma_f32_32x32x16_bf16(vf0, pf0, oacc[dsub], 0, 0, 0);
                bf16x8 vf1 = as_bf16(*(const u16x8*)&vb[drow * 64 + (c1 ^ dsw)]);
                oacc[dsub] = __builtin_amdgcn_mfma_f32_32x32x16_bf16(vf1, pf1, oacc[dsub], 0, 0, 0);
            }
            __builtin_amdgcn_s_setprio(0);
        }
    };

    STAGE(0, 0);
    for (int t = 0; t < 16; ++t) {
        __builtin_amdgcn_s_barrier();                       // all waves done with t-1
        if (t + 1 < 16) {
            STAGE(t + 1, (t + 1) & 1);
            asm volatile("s_waitcnt vmcnt(4)" ::: "memory");   // tile t's 4 loads landed
        } else {
            asm volatile("s_waitcnt vmcnt(0)" ::: "memory");
        }
        __builtin_amdgcn_s_barrier();                       // tile t visible
        tile(t, t & 1);
    }

    // ---- combine kv-groups through LDS (aliases K/V area) ----
    float* Oex = (float*)smem;                 // [4 strips][64 d][32 q]
    float* lsum = (float*)(smem + 32768);      // [4 strips][32 q]
    __syncthreads();
    if (g == 1) {
#pragma unroll
        for (int dsub = 0; dsub < 2; ++dsub)
#pragma unroll
            for (int rg = 0; rg < 4; ++rg)
#pragma unroll
                for (int rr = 0; rr < 4; ++rr) {
                    int d = dsub * 32 + hi4 + rr + 8 * rg;
                    Oex[ws * 2048 + d * 32 + l31] = oacc[dsub][rg * 4 + rr];
                }
        float lB = l_run + __shfl_xor(l_run, 32);
        if (lane < 32) lsum[ws * 32 + lane] = lB;
    }
    __syncthreads();
    if (g == 0) {
        float lt = l_run + __shfl_xor(l_run, 32) + lsum[ws * 32 + l31];
        float inv = 1.0f / lt;
        u16* cp = ctx + ((size_t)b * S_LEN + qr0 + l31) * HDIM + h * HD;
#pragma unroll
        for (int dsub = 0; dsub < 2; ++dsub)
#pragma unroll
            for (int rg = 0; rg < 4; ++rg) {
                u16x4 o;
#pragma unroll
                for (int rr = 0; rr < 4; ++rr) {
                    int d = dsub * 32 + hi4 + rr + 8 * rg;
                    float v = oacc[dsub][rg * 4 + rr] + Oex[ws * 2048 + d * 32 + l31];
                    o[rr] = f2bf(v * inv);
                }
                *(u16x4*)(cp + dsub * 32 + hi4 + 8 * rg) = o;
            }
    }
}

// ---------------- residual + layernorm ----------------
__global__ __launch_bounds__(256) void resid_ln(const float* __restrict__ hs, const float* __restrict__ proj,
                                                const float* __restrict__ g, const float* __restrict__ be,
                                                float* __restrict__ out) {
    int row = blockIdx.x, tid = threadIdx.x;
    int base = row * HDIM + tid * 4;
    f32x4 a = *(const f32x4*)(hs + base);
    f32x4 p = *(const f32x4*)(proj + base);
    f32x4 x = a + p;
    float s = x[0] + x[1] + x[2] + x[3];
    float sq = x[0] * x[0] + x[1] * x[1] + x[2] * x[2] + x[3] * x[3];
#pragma unroll
    for (int m = 1; m < 64; m <<= 1) {
        s += __shfl_xor(s, m);
        sq += __shfl_xor(sq, m);
    }
    __shared__ float red[8];
    int wave = tid >> 6, lane = tid & 63;
    if (lane == 0) { red[wave] = s; red[4 + wave] = sq; }
    __syncthreads();
    s = red[0] + red[1] + red[2] + red[3];
    sq = red[4] + red[5] + red[6] + red[7];
    float mean = s * (1.0f / 1024.0f);
    float var = sq * (1.0f / 1024.0f) - mean * mean;
    float rstd = rsqrtf(fmaxf(var, 0.f) + 1e-12f);
    f32x4 gg = *(const f32x4*)(g + tid * 4);
    f32x4 bb = *(const f32x4*)(be + tid * 4);
    f32x4 o;
#pragma unroll
    for (int j = 0; j < 4; j++) o[j] = (x[j] - mean) * rstd * gg[j] + bb[j];
    *(f32x4*)(out + base) = o;
}

extern "C" void kernel_launch(void* const* d_in, const int* in_sizes, int n_in,
                              void* d_out, int out_size, void* d_ws, size_t ws_size,
                              hipStream_t stream) {
    const float* hs    = (const float*)d_in[0];
    const float* amask = (const float*)d_in[1];
    const float* Wq    = (const float*)d_in[2];
    const float* bq    = (const float*)d_in[3];
    const float* Wk    = (const float*)d_in[4];
    const float* bk    = (const float*)d_in[5];
    const float* Wv    = (const float*)d_in[6];
    const float* bv    = (const float*)d_in[7];
    const float* Wd    = (const float*)d_in[8];
    const float* bd    = (const float*)d_in[9];
    const float* gamma = (const float*)d_in[10];
    const float* beta  = (const float*)d_in[11];

    char* ws = (char*)d_ws;
    u16*   hsb   = (u16*)(ws);                       // 8 MB: hs bf16 [4096][1024]
    u16*   Wqkvb = (u16*)(ws + ((size_t)8 << 20));   // 6 MB: [3072][1024]
    u16*   Wdb   = (u16*)(ws + ((size_t)14 << 20));  // 2 MB
    u16*   qkv   = (u16*)(ws + ((size_t)16 << 20));  // q,k planes [bh][s][d]; plane 2 = V^T [bh][d][s]
    u16*   vt    = qkv + 2 * (size_t)QKV_STRIDE;
    u16*   ctx   = (u16*)(ws + ((size_t)40 << 20));  // 8 MB: [4096][1024]
    float* proj  = (float*)(ws + ((size_t)48 << 20));// 16 MB
    float* b3    = (float*)(ws + ((size_t)64 << 20));// 12 KB

    prep<<<8204, 256, 0, stream>>>(hs, Wq, Wk, Wv, Wd, bq, bk, bv, hsb, Wqkvb, Wdb, b3);

    // QKV projection: [4096,1024] x [3072,1024]^T ; V written transposed
    gemm_bt<0><<<dim3(24, 32), 256, 0, stream>>>(hsb, Wqkvb, b3, qkv, vt, nullptr, MTOK, 3072, HDIM);

    // attention
    flash_attn6<<<512, 512, 0, stream>>>(qkv, vt, amask, ctx);

    // output projection: [4096,1024] x [1024,1024]^T -> f32
    gemm_bt<1><<<dim3(8, 32), 256, 0, stream>>>(ctx, Wdb, bd, nullptr, nullptr, proj, MTOK, HDIM, HDIM);

    // residual + layernorm
    resid_ln<<<MTOK, 256, 0, stream>>>(hs, proj, gamma, beta, (float*)d_out);
}